// Round 1
// baseline (273.706 us; speedup 1.0000x reference)
//
#include <hip/hip_runtime.h>

#define B_ROWS 4096
#define N_COLS 8192
#define BLOCK  256

// One block per row: 5 fused reductions + per-row loss.
__global__ __launch_bounds__(BLOCK) void row_pearson_kernel(
    const float* __restrict__ preds,
    const float* __restrict__ labels,
    float* __restrict__ row_loss)
{
    const int row = blockIdx.x;
    const int tid = threadIdx.x;

    const float4* p4 = reinterpret_cast<const float4*>(preds  + (size_t)row * N_COLS);
    const float4* l4 = reinterpret_cast<const float4*>(labels + (size_t)row * N_COLS);

    float sx = 0.f, sy = 0.f, sxy = 0.f, sxx = 0.f, syy = 0.f;

    // 8192 / 4 = 2048 float4 per row; 256 threads -> 8 iters, coalesced.
    #pragma unroll
    for (int i = 0; i < N_COLS / 4 / BLOCK; ++i) {
        const float4 x = p4[tid + i * BLOCK];
        const float4 y = l4[tid + i * BLOCK];
        sx  += x.x + x.y + x.z + x.w;
        sy  += y.x + y.y + y.z + y.w;
        sxy += x.x * y.x + x.y * y.y + x.z * y.z + x.w * y.w;
        sxx += x.x * x.x + x.y * x.y + x.z * x.z + x.w * x.w;
        syy += y.x * y.x + y.y * y.y + y.z * y.z + y.w * y.w;
    }

    // 64-lane wave reduction (wave = 64 on gfx950).
    #pragma unroll
    for (int off = 32; off > 0; off >>= 1) {
        sx  += __shfl_down(sx,  off);
        sy  += __shfl_down(sy,  off);
        sxy += __shfl_down(sxy, off);
        sxx += __shfl_down(sxx, off);
        syy += __shfl_down(syy, off);
    }

    __shared__ float smem[4][5];   // 4 waves per block
    const int wave = tid >> 6;
    const int lane = tid & 63;
    if (lane == 0) {
        smem[wave][0] = sx;  smem[wave][1] = sy;  smem[wave][2] = sxy;
        smem[wave][3] = sxx; smem[wave][4] = syy;
    }
    __syncthreads();

    if (tid == 0) {
        float tx = 0.f, ty = 0.f, txy = 0.f, txx = 0.f, tyy = 0.f;
        #pragma unroll
        for (int w = 0; w < BLOCK / 64; ++w) {
            tx  += smem[w][0]; ty  += smem[w][1]; txy += smem[w][2];
            txx += smem[w][3]; tyy += smem[w][4];
        }
        const float Nf  = (float)N_COLS;
        const float num = Nf * txy - tx * ty;
        const float den = sqrtf((Nf * txx - tx * tx) * (Nf * tyy - ty * ty));
        row_loss[row] = 1.0f - num / den;
    }
}

// Reduce 4096 per-row losses to the mean. Single block.
__global__ __launch_bounds__(BLOCK) void mean_kernel(
    const float* __restrict__ row_loss,
    float* __restrict__ out)
{
    const int tid = threadIdx.x;
    float s = 0.f;
    #pragma unroll
    for (int i = 0; i < B_ROWS / BLOCK; ++i)
        s += row_loss[tid + i * BLOCK];

    #pragma unroll
    for (int off = 32; off > 0; off >>= 1)
        s += __shfl_down(s, off);

    __shared__ float smem[4];
    const int wave = tid >> 6;
    const int lane = tid & 63;
    if (lane == 0) smem[wave] = s;
    __syncthreads();

    if (tid == 0) {
        float t = smem[0] + smem[1] + smem[2] + smem[3];
        out[0] = t / (float)B_ROWS;
    }
}

extern "C" void kernel_launch(void* const* d_in, const int* in_sizes, int n_in,
                              void* d_out, int out_size, void* d_ws, size_t ws_size,
                              hipStream_t stream) {
    const float* preds  = (const float*)d_in[0];
    const float* labels = (const float*)d_in[1];
    float* row_loss = (float*)d_ws;      // 4096 floats of scratch
    float* out      = (float*)d_out;

    row_pearson_kernel<<<B_ROWS, BLOCK, 0, stream>>>(preds, labels, row_loss);
    mean_kernel<<<1, BLOCK, 0, stream>>>(row_loss, out);
}

// Round 2
// 271.604 us; speedup vs baseline: 1.0077x; 1.0077x over previous
//
#include <hip/hip_runtime.h>

#define B_ROWS 4096
#define N_COLS 8192
#define BLOCK  256
#define VPT    (N_COLS / 4 / BLOCK)   // float4 loads per thread per input = 8

// One block per row: 5 fused reductions + per-row loss.
// Key change vs R1: issue ALL 16 global_load_dwordx4 before consuming any,
// so the wave has 16 loads (256 B) in flight instead of ~4. R1's 32-VGPR
// allocation serialized the load->accumulate chain (latency-bound, 98 us,
// VALUBusy 7%).
__global__ __launch_bounds__(BLOCK) void row_pearson_kernel(
    const float* __restrict__ preds,
    const float* __restrict__ labels,
    float* __restrict__ row_loss)
{
    const int row = blockIdx.x;
    const int tid = threadIdx.x;

    const float4* p4 = reinterpret_cast<const float4*>(preds  + (size_t)row * N_COLS);
    const float4* l4 = reinterpret_cast<const float4*>(labels + (size_t)row * N_COLS);

    // Issue all loads first — 16 independent global_load_dwordx4.
    float4 x[VPT], y[VPT];
    #pragma unroll
    for (int i = 0; i < VPT; ++i) x[i] = p4[tid + i * BLOCK];
    #pragma unroll
    for (int i = 0; i < VPT; ++i) y[i] = l4[tid + i * BLOCK];

    float sx = 0.f, sy = 0.f, sxy = 0.f, sxx = 0.f, syy = 0.f;
    #pragma unroll
    for (int i = 0; i < VPT; ++i) {
        const float4 a = x[i];
        const float4 b = y[i];
        sx  += a.x + a.y + a.z + a.w;
        sy  += b.x + b.y + b.z + b.w;
        sxy += a.x * b.x + a.y * b.y + a.z * b.z + a.w * b.w;
        sxx += a.x * a.x + a.y * a.y + a.z * a.z + a.w * a.w;
        syy += b.x * b.x + b.y * b.y + b.z * b.z + b.w * b.w;
    }

    // 64-lane wave reduction (wave = 64 on gfx950).
    #pragma unroll
    for (int off = 32; off > 0; off >>= 1) {
        sx  += __shfl_down(sx,  off);
        sy  += __shfl_down(sy,  off);
        sxy += __shfl_down(sxy, off);
        sxx += __shfl_down(sxx, off);
        syy += __shfl_down(syy, off);
    }

    __shared__ float smem[4][5];   // 4 waves per block
    const int wave = tid >> 6;
    const int lane = tid & 63;
    if (lane == 0) {
        smem[wave][0] = sx;  smem[wave][1] = sy;  smem[wave][2] = sxy;
        smem[wave][3] = sxx; smem[wave][4] = syy;
    }
    __syncthreads();

    if (tid == 0) {
        float tx = 0.f, ty = 0.f, txy = 0.f, txx = 0.f, tyy = 0.f;
        #pragma unroll
        for (int w = 0; w < BLOCK / 64; ++w) {
            tx  += smem[w][0]; ty  += smem[w][1]; txy += smem[w][2];
            txx += smem[w][3]; tyy += smem[w][4];
        }
        const float Nf  = (float)N_COLS;
        const float num = Nf * txy - tx * ty;
        const float den = sqrtf((Nf * txx - tx * tx) * (Nf * tyy - ty * ty));
        row_loss[row] = 1.0f - num / den;
    }
}

// Reduce 4096 per-row losses to the mean. Single block.
__global__ __launch_bounds__(BLOCK) void mean_kernel(
    const float* __restrict__ row_loss,
    float* __restrict__ out)
{
    const int tid = threadIdx.x;

    // Issue all 16 loads up front too.
    float v[B_ROWS / BLOCK];
    #pragma unroll
    for (int i = 0; i < B_ROWS / BLOCK; ++i)
        v[i] = row_loss[tid + i * BLOCK];

    float s = 0.f;
    #pragma unroll
    for (int i = 0; i < B_ROWS / BLOCK; ++i)
        s += v[i];

    #pragma unroll
    for (int off = 32; off > 0; off >>= 1)
        s += __shfl_down(s, off);

    __shared__ float smem[4];
    const int wave = tid >> 6;
    const int lane = tid & 63;
    if (lane == 0) smem[wave] = s;
    __syncthreads();

    if (tid == 0) {
        float t = smem[0] + smem[1] + smem[2] + smem[3];
        out[0] = t / (float)B_ROWS;
    }
}

extern "C" void kernel_launch(void* const* d_in, const int* in_sizes, int n_in,
                              void* d_out, int out_size, void* d_ws, size_t ws_size,
                              hipStream_t stream) {
    const float* preds  = (const float*)d_in[0];
    const float* labels = (const float*)d_in[1];
    float* row_loss = (float*)d_ws;      // 4096 floats of scratch
    float* out      = (float*)d_out;

    row_pearson_kernel<<<B_ROWS, BLOCK, 0, stream>>>(preds, labels, row_loss);
    mean_kernel<<<1, BLOCK, 0, stream>>>(row_loss, out);
}